// Round 2
// baseline (513.813 us; speedup 1.0000x reference)
//
#include <hip/hip_runtime.h>
#include <math.h>

// Problem constants (B=8, C=8*16+70=198, H=W=256, J=16)
#define NB 8
#define NC 198
#define HW 65536           // 256*256
#define NJ 16
#define THRESH 0.75f

// Channel layout of seg_out:
//   nocs: 0..2, mask: 3, loc: 4..51 (j*3+c), pose: 52..99, skin: 100..117 (18 ch), conf: 118..133
// Channels 134..197 unused.

constexpr int JG = 4;                 // joints per reduction group
constexpr int NGRP = NJ / JG;         // 4 groups
constexpr int K1_BLOCKS_PER = 32;     // blocks per (b, group)
constexpr int K1_THREADS = 256;
constexpr int NVEC = HW / 4;          // float4 chunks per channel = 16384

__device__ __forceinline__ float sigm(float x) { return 1.0f / (1.0f + expf(-x)); }

// ---------------- Kernel 1: vote reductions ----------------
// For each (b, j): sums[.][0] = sum sigmoid(conf)*mask
//                  sums[.][1..3] = sum loc_c * mask^2 * sigmoid(conf)
//                  sums[.][4..6] = sum pose_c * mask^2 * sigmoid(conf)
__global__ __launch_bounds__(K1_THREADS)
void k1_vote(const float* __restrict__ in, float* __restrict__ sums) {
    const int blk = blockIdx.x;
    const int chunk = blk % K1_BLOCKS_PER;
    const int grp = (blk / K1_BLOCKS_PER) % NGRP;
    const int b = blk / (K1_BLOCKS_PER * NGRP);
    const int j0 = grp * JG;
    const float* base = in + (size_t)b * NC * HW;
    const float4* m4p = (const float4*)(base + (size_t)3 * HW);

    float acc[JG][7];
#pragma unroll
    for (int a = 0; a < JG; ++a)
#pragma unroll
        for (int k = 0; k < 7; ++k) acc[a][k] = 0.0f;

    for (int v = chunk * K1_THREADS + (int)threadIdx.x; v < NVEC; v += K1_BLOCKS_PER * K1_THREADS) {
        float4 mr = m4p[v];
        float m0 = sigm(mr.x), m1 = sigm(mr.y), m2 = sigm(mr.z), m3 = sigm(mr.w);
#pragma unroll
        for (int jj = 0; jj < JG; ++jj) {
            const int j = j0 + jj;
            float4 cr = ((const float4*)(base + (size_t)(118 + j) * HW))[v];
            float s0 = sigm(cr.x) * m0, s1 = sigm(cr.y) * m1;
            float s2 = sigm(cr.z) * m2, s3 = sigm(cr.w) * m3;
            acc[jj][0] += (s0 + s1) + (s2 + s3);
            float w0 = s0 * m0, w1 = s1 * m1, w2 = s2 * m2, w3 = s3 * m3;
#pragma unroll
            for (int c = 0; c < 3; ++c) {
                float4 lr = ((const float4*)(base + (size_t)(4 + j * 3 + c) * HW))[v];
                acc[jj][1 + c] += (lr.x * w0 + lr.y * w1) + (lr.z * w2 + lr.w * w3);
                float4 pr = ((const float4*)(base + (size_t)(52 + j * 3 + c) * HW))[v];
                acc[jj][4 + c] += (pr.x * w0 + pr.y * w1) + (pr.z * w2 + pr.w * w3);
            }
        }
    }

    // Block reduce: wave shuffle -> LDS -> atomicAdd (32 blocks contend per sum, trivial)
    __shared__ float lds[JG * 7][4];
    const int lane = threadIdx.x & 63;
    const int wv = threadIdx.x >> 6;
#pragma unroll
    for (int s = 0; s < JG * 7; ++s) {
        float val = acc[s / 7][s % 7];
#pragma unroll
        for (int off = 32; off > 0; off >>= 1) val += __shfl_down(val, off, 64);
        if (lane == 0) lds[s][wv] = val;
    }
    __syncthreads();
    if ((int)threadIdx.x < JG * 7) {
        const int jj = threadIdx.x / 7, k = threadIdx.x % 7;
        float val = lds[threadIdx.x][0] + lds[threadIdx.x][1] + lds[threadIdx.x][2] + lds[threadIdx.x][3];
        atomicAdd(&sums[((b * NJ) + j0 + jj) * 7 + k], val);
    }
}

// ---------------- Kernel 2: Rodrigues + repose matrices ----------------
// One thread per (b, j), j in [0, 17). j==16 is the zero-padded joint.
__global__ void k2_repose(const float* __restrict__ sums, float* __restrict__ rep) {
    int t = blockIdx.x * blockDim.x + threadIdx.x;
    if (t >= NB * (NJ + 1)) return;
    int b = t / (NJ + 1), j = t - b * (NJ + 1);
    float lx = 0.f, ly = 0.f, lz = 0.f, px = 0.f, py = 0.f, pz = 0.f;
    if (j < NJ) {
        const float* s = sums + ((b * NJ) + j) * 7;
        float denom = s[0] + 1e-5f;
        lx = s[1] / denom; ly = s[2] / denom; lz = s[3] / denom;
        px = s[4] / denom; py = s[5] / denom; pz = s[6] / denom;
    }
    // R = rodrigues(-pose); note: angle = ||v + 1e-8|| (elementwise add), axis = v/angle
    float vx = -px, vy = -py, vz = -pz;
    float e0 = vx + 1e-8f, e1 = vy + 1e-8f, e2 = vz + 1e-8f;
    float ang = sqrtf(e0 * e0 + e1 * e1 + e2 * e2);
    float ia = 1.0f / ang;
    float ux = vx * ia, uy = vy * ia, uz = vz * ia;
    float cc = cosf(ang), ss = sinf(ang), oc = 1.0f - cc;
    float r00 = cc + oc * ux * ux, r01 = -ss * uz + oc * ux * uy, r02 = ss * uy + oc * ux * uz;
    float r10 = ss * uz + oc * uy * ux, r11 = cc + oc * uy * uy, r12 = -ss * ux + oc * uy * uz;
    float r20 = -ss * uy + oc * uz * ux, r21 = ss * ux + oc * uz * uy, r22 = cc + oc * uz * uz;
    float tx = lx - (r00 * lx + r01 * ly + r02 * lz);
    float ty = ly - (r10 * lx + r11 * ly + r12 * lz);
    float tz = lz - (r20 * lx + r21 * ly + r22 * lz);
    float* o = rep + (size_t)t * 16;
    o[0] = r00; o[1] = r01; o[2] = r02; o[3] = tx;
    o[4] = r10; o[5] = r11; o[6] = r12; o[7] = ty;
    o[8] = r20; o[9] = r21; o[10] = r22; o[11] = tz;
    o[12] = 0.f; o[13] = 0.f; o[14] = 0.f; o[15] = 1.f;
}

// ---------------- Kernel 3: per-pixel argmax + affine transform ----------------
__global__ __launch_bounds__(256)
void k3_apply(const float* __restrict__ in, const float* __restrict__ rep, float* __restrict__ out) {
    int idx = blockIdx.x * 256 + threadIdx.x;   // 0 .. NB*NVEC-1
    int b = idx / NVEC;
    int v = idx - b * NVEC;
    const float* base = in + (size_t)b * NC * HW;
    float4 mr = ((const float4*)(base + (size_t)3 * HW))[v];
    float4 n0 = ((const float4*)(base + (size_t)0 * HW))[v];
    float4 n1 = ((const float4*)(base + (size_t)1 * HW))[v];
    float4 n2 = ((const float4*)(base + (size_t)2 * HW))[v];

    // argmax over 18 skin channels, first-max-wins (strict >)
    float bestv[4];
    int besti[4];
    {
        float4 s0 = ((const float4*)(base + (size_t)100 * HW))[v];
        bestv[0] = s0.x; bestv[1] = s0.y; bestv[2] = s0.z; bestv[3] = s0.w;
        besti[0] = besti[1] = besti[2] = besti[3] = 0;
    }
#pragma unroll
    for (int ch = 1; ch < 18; ++ch) {
        float4 sv = ((const float4*)(base + (size_t)(100 + ch) * HW))[v];
        if (sv.x > bestv[0]) { bestv[0] = sv.x; besti[0] = ch; }
        if (sv.y > bestv[1]) { bestv[1] = sv.y; besti[1] = ch; }
        if (sv.z > bestv[2]) { bestv[2] = sv.z; besti[2] = ch; }
        if (sv.w > bestv[3]) { bestv[3] = sv.w; besti[3] = ch; }
    }
    float mm[4] = { sigm(mr.x), sigm(mr.y), sigm(mr.z), sigm(mr.w) };
    float nx[4] = { n0.x, n0.y, n0.z, n0.w };
    float ny[4] = { n1.x, n1.y, n1.z, n1.w };
    float nz[4] = { n2.x, n2.y, n2.z, n2.w };
    float ox[4], oy[4], oz[4];
#pragma unroll
    for (int k = 0; k < 4; ++k) {
        bool valid = mm[k] > THRESH;
        float ax = valid ? nx[k] : 0.0f;
        float ay = valid ? ny[k] : 0.0f;
        float az = valid ? nz[k] : 0.0f;
        bool v3 = (ax > 0.0f) && (ay > 0.0f) && (az > 0.0f);
        float rx = 0.f, ry = 0.f, rz = 0.f;
        if (v3 && besti[k] > 0) {
            const float* T = rep + ((size_t)b * (NJ + 1) + (besti[k] - 1)) * 16;
            rx = T[0] * ax + T[1] * ay + T[2] * az + T[3];
            ry = T[4] * ax + T[5] * ay + T[6] * az + T[7];
            rz = T[8] * ax + T[9] * ay + T[10] * az + T[11];
        }
        ox[k] = rx; oy[k] = ry; oz[k] = rz;
    }
    float* ob = out + (size_t)b * 3 * HW;
    ((float4*)(ob))[v]            = make_float4(ox[0], ox[1], ox[2], ox[3]);
    ((float4*)(ob + HW))[v]       = make_float4(oy[0], oy[1], oy[2], oy[3]);
    ((float4*)(ob + 2 * HW))[v]   = make_float4(oz[0], oz[1], oz[2], oz[3]);
}

extern "C" void kernel_launch(void* const* d_in, const int* in_sizes, int n_in,
                              void* d_out, int out_size, void* d_ws, size_t ws_size,
                              hipStream_t stream) {
    const float* in = (const float*)d_in[0];
    float* out = (float*)d_out;
    float* sums = (float*)d_ws;                          // NB*NJ*7 = 896 floats
    float* rep = (float*)((char*)d_ws + 4096);           // NB*17*16 = 2176 floats

    // ws is re-poisoned to 0xAA before every timed launch -> must zero the sums.
    hipMemsetAsync(d_ws, 0, NB * NJ * 7 * sizeof(float), stream);
    k1_vote<<<NB * NGRP * K1_BLOCKS_PER, K1_THREADS, 0, stream>>>(in, sums);
    k2_repose<<<1, 256, 0, stream>>>(sums, rep);
    k3_apply<<<(NB * NVEC) / 256, 256, 0, stream>>>(in, rep, out);
}